// Round 4
// baseline (270.494 us; speedup 1.0000x reference)
//
#include <hip/hip_runtime.h>
#include <hip/hip_bf16.h>

#define N_NODES 50000
#define N_EDGES 250000
#define DIM 32

// flags[0..7]: 1 if float input j is fp32, 0 if bf16.
//   order: x, ea, node_W, node_b, l1_W, l1_b, root, conv_b
// flags[8]: 1 if edge_index is int64, 0 if int32.
__global__ void detect_kernel(
    const void* x, const void* ea, const void* nW, const void* nb,
    const void* lW, const void* lb, const void* rt, const void* cb,
    const int* __restrict__ ei, int* __restrict__ flags)
{
    if (threadIdx.x != 0 || blockIdx.x != 0) return;
    const void* ptrs[8]  = {x, ea, nW, nb, lW, lb, rt, cb};
    const int   sizes[8] = {N_NODES, N_EDGES, 32, 32, 1024, 1024, 1024, 32};
    for (int j = 0; j < 8; ++j) {
        const unsigned short* hs = (const unsigned short*)ptrs[j];
        int K = sizes[j] < 128 ? sizes[j] : 128;   // K uint16 = K*2 bytes <= bf16 buffer size
        int isf32 = 0;
        for (int k = 0; k < K; ++k) {
            unsigned int w = ((unsigned int)hs[k]) << 16;   // decode as bf16
            float v = __uint_as_float(w);
            if (!(fabsf(v) <= 50.0f)) { isf32 = 1; break; } // catches huge & NaN
        }
        flags[j] = isf32;
    }
    int allz = 1;   // int64 LE with values < 2^31 -> odd int32 words all 0
    for (int k = 0; k < 64; ++k)
        if (ei[2 * k + 1] != 0) { allz = 0; break; }
    flags[8] = allz;
}

__device__ __forceinline__ float ldf(const void* p, int i, int isf32) {
    return isf32 ? ((const float*)p)[i]
                 : __bfloat162float(((const __hip_bfloat16*)p)[i]);
}
__device__ __forceinline__ int ldi(const int* __restrict__ ei, int i, int i64) {
    return i64 ? ei[2 * i] : ei[i];
}
__device__ __forceinline__ int clamp_idx(int v) {
    v = v < 0 ? 0 : v;
    return v >= N_NODES ? N_NODES - 1 : v;
}

// --- in-degree count: cnt[dst] += 1 ---
__global__ __launch_bounds__(256) void deg_kernel(
    const int* __restrict__ ei, const int* __restrict__ flags,
    float* __restrict__ cnt)
{
    int e = blockIdx.x * blockDim.x + threadIdx.x;
    if (e >= N_EDGES) return;
    int d = clamp_idx(ldi(ei, N_EDGES + e, flags[8]));
    atomicAdd(&cnt[d], 1.0f);
}

// --- init: h[n,d] = x[n] * node_W[d] + node_b[d] ---
__global__ __launch_bounds__(256) void init_h_kernel(
    const void* __restrict__ x,
    const void* __restrict__ node_W,
    const void* __restrict__ node_b,
    const int* __restrict__ flags,
    float* __restrict__ h)
{
    int t = blockIdx.x * blockDim.x + threadIdx.x;
    if (t >= N_NODES * DIM) return;
    int n = t >> 5;
    int d = t & 31;
    h[t] = fmaf(ldf(x, n, flags[0]), ldf(node_W, d, flags[2]), ldf(node_b, d, flags[3]));
}

// --- fused per-node GEMMs: hr = relu(h); u = hr@L1W, v = hr@L1B,
//     aggr = max(cnt,1)*(hr@root)  (pre-seeds the scaled root term so combine
//     is one divide and no aggr memset is needed) ---
// block = 256 threads = 8 nodes x 32 lanes. 3x 32x32 fp32 weights in LDS.
__global__ __launch_bounds__(256) void gemm3_kernel(
    const float* __restrict__ h,
    const void* __restrict__ l1_W,
    const void* __restrict__ l1_b,
    const void* __restrict__ root,
    const int* __restrict__ flags,
    const float* __restrict__ cnt,
    float* __restrict__ u, float* __restrict__ v, float* __restrict__ aggr)
{
    __shared__ float sW[DIM * DIM];
    __shared__ float sB[DIM * DIM];
    __shared__ float sR[DIM * DIM];
    __shared__ float sh[8][DIM + 1];

    int tid = threadIdx.x;
    int fW = flags[4], fB = flags[5], fR = flags[6];
    for (int k = tid; k < DIM * DIM; k += 256) {
        sW[k] = ldf(l1_W, k, fW);
        sB[k] = ldf(l1_b, k, fB);
        sR[k] = ldf(root, k, fR);
    }
    int local = tid >> 5;   // 0..7
    int lane  = tid & 31;   // 0..31
    int n = blockIdx.x * 8 + local;
    if (n < N_NODES) {
        float hv = h[n * DIM + lane];
        sh[local][lane] = hv > 0.0f ? hv : 0.0f;   // relu
    }
    __syncthreads();
    if (n >= N_NODES) return;

    float au = 0.0f, av = 0.0f, ar = 0.0f;
    #pragma unroll
    for (int i = 0; i < DIM; ++i) {
        float hv = sh[local][i];                   // broadcast read
        au = fmaf(hv, sW[i * DIM + lane], au);     // conflict-free
        av = fmaf(hv, sB[i * DIM + lane], av);
        ar = fmaf(hv, sR[i * DIM + lane], ar);
    }
    float c = cnt[n];
    c = c < 1.0f ? 1.0f : c;
    u[n * DIM + lane] = au;
    v[n * DIM + lane] = av;
    aggr[n * DIM + lane] = c * ar;   // (sum_msg + c*r)/c == sum/c + r
}

// --- edge scatter: aggr[dst] += ea[e]*u[src] + v[src]  (32 lanes per edge) ---
__global__ __launch_bounds__(256) void edge_kernel(
    const int* __restrict__ ei,
    const void* __restrict__ ea,
    const int* __restrict__ flags,
    const float* __restrict__ u,
    const float* __restrict__ v,
    float* __restrict__ aggr)
{
    int t = blockIdx.x * blockDim.x + threadIdx.x;
    int e = t >> 5;
    if (e >= N_EDGES) return;
    int lane = t & 31;
    int i64 = flags[8];
    int s = clamp_idx(ldi(ei, e, i64));
    int d = clamp_idx(ldi(ei, N_EDGES + e, i64));
    float a = ldf(ea, e, flags[1]);
    float msg = fmaf(a, u[s * DIM + lane], v[s * DIM + lane]);
    atomicAdd(&aggr[d * DIM + lane], msg);
}

// --- combine: h = aggr/max(cnt,1) + conv_b; optionally emit fp32 out ---
__global__ __launch_bounds__(256) void combine_kernel(
    const float* __restrict__ aggr,
    const float* __restrict__ cnt,
    const void* __restrict__ conv_b,
    const int* __restrict__ flags,
    float* __restrict__ h,
    float* __restrict__ out)   // nullptr except last layer; OUTPUT IS FP32
{
    int t = blockIdx.x * blockDim.x + threadIdx.x;
    if (t >= N_NODES * DIM) return;
    int n = t >> 5;
    int d = t & 31;
    float c = cnt[n];
    c = c < 1.0f ? 1.0f : c;
    float val = aggr[t] / c + ldf(conv_b, d, flags[7]);
    h[t] = val;
    if (out) out[t] = val;
}

extern "C" void kernel_launch(void* const* d_in, const int* in_sizes, int n_in,
                              void* d_out, int out_size, void* d_ws, size_t ws_size,
                              hipStream_t stream) {
    // Locate inputs by size pattern (skip scalar args):
    // 50000(x), 500000(edge_index), 250000(ea), 32(node_W), 32(node_b),
    // 1024(l1_W), 1024(l1_b), 1024(root), 32(conv_b)
    const void* p[16];
    int np_ = 0;
    for (int i = 0; i < n_in && np_ < 16; ++i)
        if (in_sizes[i] != 1) p[np_++] = d_in[i];

    const void* x      = p[0];
    const int*  ei     = (const int*)p[1];
    const void* ea     = p[2];
    const void* node_W = p[3];
    const void* node_b = p[4];
    const void* l1_W   = p[5];
    const void* l1_b   = p[6];
    const void* root   = p[7];
    const void* conv_b = p[8];
    float* out = (float*)d_out;

    const int ND = N_NODES * DIM;
    float* ws   = (float*)d_ws;
    float* h    = ws;            // N*D
    float* u    = h + ND;        // N*D
    float* v    = u + ND;        // N*D
    float* aggr = v + ND;        // N*D
    float* cnt  = aggr + ND;     // N
    int*   flags = (int*)(cnt + N_NODES);  // 9 ints

    detect_kernel<<<1, 64, 0, stream>>>(x, ea, node_W, node_b, l1_W, l1_b,
                                        root, conv_b, ei, flags);
    hipMemsetAsync(cnt, 0, N_NODES * sizeof(float), stream);
    deg_kernel<<<(N_EDGES + 255) / 256, 256, 0, stream>>>(ei, flags, cnt);
    init_h_kernel<<<(ND + 255) / 256, 256, 0, stream>>>(x, node_W, node_b, flags, h);

    const int gemm_blocks = (N_NODES + 7) / 8;           // 6250
    const int edge_blocks = (N_EDGES * DIM + 255) / 256; // 31250

    for (int layer = 0; layer < 3; ++layer) {
        gemm3_kernel<<<gemm_blocks, 256, 0, stream>>>(h, l1_W, l1_b, root, flags,
                                                      cnt, u, v, aggr);
        edge_kernel<<<edge_blocks, 256, 0, stream>>>(ei, ea, flags, u, v, aggr);
        combine_kernel<<<(ND + 255) / 256, 256, 0, stream>>>(
            aggr, cnt, conv_b, flags, h, layer == 2 ? out : nullptr);
    }
}